// Round 9
// baseline (18597.441 us; speedup 1.0000x reference)
//
#include <hip/hip_runtime.h>
#include <hip/hip_bf16.h>

#define LAT 128
#define H 256
#define OUTD 64
#define SEQ 512

typedef short bf16x8 __attribute__((ext_vector_type(8)));
typedef float f32x4  __attribute__((ext_vector_type(4)));
typedef unsigned long long u64;
typedef unsigned u32;

__device__ __forceinline__ float sigm(float x)  { return 1.f / (1.f + __expf(-x)); }
__device__ __forceinline__ float tanhf_(float x){ return 1.f - 2.f / (__expf(2.f * x) + 1.f); }

__device__ __forceinline__ short f2bs(float x) {
    __hip_bfloat16 b = __float2bfloat16(x);
    return *reinterpret_cast<short*>(&b);
}
__device__ __forceinline__ float bs2f(unsigned short h) {
    u32 b = ((u32)h) << 16;
    float f; __builtin_memcpy(&f, &b, 4); return f;
}
__device__ __forceinline__ u32 f2pair(float a, float b) {
    return ((u32)(unsigned short)f2bs(b) << 16) | (u32)(unsigned short)f2bs(a);
}

// ---------------- Prologue: pack weights into lane-ordered bf16 MFMA frags ----
// Frag layout: Wp[block][kk][lane][8 bf16]; linear frag id f = (block*8+kk)*64+lane.
// Blocks: 0..63 Whh0 m-tiles, 64..127 Wih1, 128..191 Whh1, 192..195 Wout.
// Gate-packed matrices (1024x256), m-tile mt, lane l:
//   row = (l&3)*H + mt*4 + ((l>>2)&3)   (m = c*4+g packing, proven map)
//   col = kk*32 + ((l>>4)&3)*8 + e
// Wout (64x256, natural rows): row = mt*16 + (l&15), same col map.
__global__ void lstm_pack_w(const float* __restrict__ Whh0, const float* __restrict__ Wih1,
                            const float* __restrict__ Whh1, const float* __restrict__ Wout,
                            short* __restrict__ Wp)
{
    int f = blockIdx.x * 256 + threadIdx.x;     // 196*8*64 = 100352 frags
    if (f >= 196 * 8 * 64) return;
    int l  = f & 63;
    int kk = (f >> 6) & 7;
    int b  = f >> 9;
    const float* src;
    int row;
    if (b < 192) {
        int mt = b & 63;
        const float* mats[3] = { Whh0, Wih1, Whh1 };
        src = mats[b >> 6];
        row = (l & 3) * H + mt * 4 + ((l >> 2) & 3);
    } else {
        src = Wout;
        row = (b - 192) * 16 + (l & 15);
    }
    const float* s = src + row * H + kk * 32 + ((l >> 4) & 3) * 8;
    short* d = Wp + (long)f * 8;
    #pragma unroll
    for (int e = 0; e < 8; e++) d[e] = f2bs(s[e]);
}

// ---------------- Fused kernel: one wg owns 16 batch rows, full hidden dim ----
// 16 wgs x 512 thr (8 waves, 2/SIMD). Batch rows are INDEPENDENT across the
// sequence -> zero inter-wg communication; the h0/h1 recurrences live in LDS
// with two __syncthreads per step (structural replacement for the global
// transport whose ~6300cy period resisted 8 rounds of tuning).
// Wave w owns m-tiles w*8..w*8+7 (16 hidden cols) for L0 and L1; waves 0-3
// additionally own one out-proj m-tile each (16 out cols). Weights stream
// from L2 (1.6MB/wg/step, L2-resident; 2 wgs/XCD) as pre-packed frags.
// All fragment maps / nonlinearity / bf16 numerics verbatim from the
// proven kernel; biases folded into MFMA C-init.
__global__ __launch_bounds__(512, 2)
void lstm_fused(const float* __restrict__ z,
                const float* __restrict__ Whid, const float* __restrict__ bhid,
                const float* __restrict__ Wcell, const float* __restrict__ bcell,
                const float* __restrict__ Win,  const float* __restrict__ bin,
                const float* __restrict__ Wih0, const float* __restrict__ bih0,
                const float* __restrict__ bhh0,
                const float* __restrict__ bih1, const float* __restrict__ bhh1,
                const float* __restrict__ bout,
                const short* __restrict__ Wp, float* __restrict__ out)
{
    const int bg   = blockIdx.x;          // 0..15: batch rows bg*16..+15
    const int tid  = threadIdx.x;         // 0..511
    const int w    = tid >> 6;            // wave 0..7
    const int lane = tid & 63;
    const int q    = (lane >> 4) & 3;
    const int ln   = lane & 15;
    const int myb  = bg * 16 + ln;
    const int b0   = bg * 16;
    const int w8   = w * 8;
    const int lane8 = lane * 8;

    __shared__ u32 hs0[2][16 * 132];      // h0 parity planes (row ln x 132 u32)
    __shared__ u32 hs1[2][16 * 132];      // h1 parity planes

    const short* W0p = Wp;                // Whh0 frags
    const short* W1p = Wp + 262144;       // Wih1
    const short* W2p = Wp + 524288;       // Whh1
    const short* Wop = Wp + 786432;       // Wout

    // ================= init phase (one-time, ~10us) =================
    // x0 = Win·z + bin, staged in LDS (aliases hs0; released before h-init)
    float* x0s = (float*)hs0;             // [16][256] f32 = 16KB <= sizeof(hs0)
    for (int v = tid; v < 16 * 256; v += 512) {
        int rr = v >> 8, cc = v & 255;
        const f32x4* zr = (const f32x4*)(z + (b0 + rr) * LAT);
        const f32x4* wr = (const f32x4*)(Win + cc * LAT);
        float a = bin[cc];
        for (int k4 = 0; k4 < LAT / 4; k4++) {
            f32x4 zv = zr[k4], wv = wr[k4];
            a += zv[0]*wv[0] + zv[1]*wv[1] + zv[2]*wv[2] + zv[3]*wv[3];
        }
        x0s[v] = a;
    }
    __syncthreads();

    // per-lane gate-bias packs (bf16 pairs) + cell state (fp32)
    u32 gx0p[8][2], gx1p[8][2];
    float creg0[8], creg1[8];
    {
        const f32x4* x4 = (const f32x4*)(x0s + ln * 256);
        const f32x4* zr = (const f32x4*)(z + myb * LAT);
        #pragma unroll
        for (int m = 0; m < 8; m++) {
            const int col = (w8 + m) * 4 + q;
            float gr[4];
            #pragma unroll
            for (int r = 0; r < 4; r++) {
                const int grow = r * 256 + col;
                const f32x4* wr = (const f32x4*)(Wih0 + grow * 256);
                float a = bih0[grow] + bhh0[grow];
                for (int k4 = 0; k4 < 64; k4++) {
                    f32x4 xv = x4[k4], wv = wr[k4];
                    a += xv[0]*wv[0] + xv[1]*wv[1] + xv[2]*wv[2] + xv[3]*wv[3];
                }
                gr[r] = a;
            }
            gx0p[m][0] = f2pair(gr[0], gr[1]);
            gx0p[m][1] = f2pair(gr[2], gr[3]);
            gx1p[m][0] = f2pair(bih1[col] + bhh1[col],
                                bih1[256 + col] + bhh1[256 + col]);
            gx1p[m][1] = f2pair(bih1[512 + col] + bhh1[512 + col],
                                bih1[768 + col] + bhh1[768 + col]);
            // cell init: c = Wcell·z + bcell (rows: layer*H + col)
            const f32x4* wc0 = (const f32x4*)(Wcell + col * LAT);
            const f32x4* wc1 = (const f32x4*)(Wcell + (256 + col) * LAT);
            float a0 = bcell[col], a1 = bcell[256 + col];
            for (int k4 = 0; k4 < LAT / 4; k4++) {
                f32x4 zv = zr[k4], v0 = wc0[k4], v1 = wc1[k4];
                a0 += zv[0]*v0[0] + zv[1]*v0[1] + zv[2]*v0[2] + zv[3]*v0[3];
                a1 += zv[0]*v1[0] + zv[1]*v1[1] + zv[2]*v1[2] + zv[3]*v1[3];
            }
            creg0[m] = a0; creg1[m] = a1;
        }
    }
    float bor[4] = {0.f, 0.f, 0.f, 0.f};
    if (w < 4) {
        #pragma unroll
        for (int r = 0; r < 4; r++) bor[r] = bout[w * 16 + q * 4 + r];
    }
    __syncthreads();                      // all x0 reads done; hs0 reusable

    // h-init: h(-1) = Whid·z + bhid, bf16 pairs into plane 0 of each layer.
    // 4096 pairs total; thread computes 8: p -> (layer, rr, cp)
    for (int p = tid * 8; p < tid * 8 + 8; p++) {
        int layer = p >> 11, rr = (p >> 7) & 15, cp = p & 127;
        int colA = layer * H + 2 * cp;
        const f32x4* zr = (const f32x4*)(z + (b0 + rr) * LAT);
        const f32x4* wA = (const f32x4*)(Whid + colA * LAT);
        const f32x4* wB = (const f32x4*)(Whid + (colA + 1) * LAT);
        float a0 = bhid[colA], a1 = bhid[colA + 1];
        for (int k4 = 0; k4 < LAT / 4; k4++) {
            f32x4 zv = zr[k4], vA = wA[k4], vB = wB[k4];
            a0 += zv[0]*vA[0] + zv[1]*vA[1] + zv[2]*vA[2] + zv[3]*vA[3];
            a1 += zv[0]*vB[0] + zv[1]*vB[1] + zv[2]*vB[2] + zv[3]*vB[3];
        }
        (layer ? hs1[0] : hs0[0])[rr * 132 + cp] = f2pair(a0, a1);
    }
    __syncthreads();

    // ================= steady loop: step t computes L0(t), L1(t), out(t-1) ====
    for (int t = 0; t <= SEQ; t++) {
        const int par = t & 1;            // h(t-1) in plane par; h(t) -> par^1

        // ---- layer 0: h0(t) = lstm(x0-bias-folded, h0(t-1)) ----
        if (t < SEQ) {
            bf16x8 hb[8];
            const unsigned short* p0 = (const unsigned short*)hs0[par];
            #pragma unroll
            for (int kk = 0; kk < 8; kk++)
                hb[kk] = *(const bf16x8*)(p0 + ln * 264 + kk * 32 + q * 8);
            #pragma unroll
            for (int m = 0; m < 8; m++) {
                const int mt = w8 + m;
                const short* ap = W0p + mt * 4096 + lane8;
                bf16x8 af[8];
                #pragma unroll
                for (int kk = 0; kk < 8; kk++)
                    af[kk] = *(const bf16x8*)(ap + kk * 512);
                f32x4 acc;
                acc[0] = bs2f((unsigned short)(gx0p[m][0] & 0xFFFFu));
                acc[1] = bs2f((unsigned short)(gx0p[m][0] >> 16));
                acc[2] = bs2f((unsigned short)(gx0p[m][1] & 0xFFFFu));
                acc[3] = bs2f((unsigned short)(gx0p[m][1] >> 16));
                #pragma unroll
                for (int kk = 0; kk < 8; kk++)
                    acc = __builtin_amdgcn_mfma_f32_16x16x32_bf16(af[kk], hb[kk], acc, 0, 0, 0);
                float i_ = sigm(acc[0]);
                float f_ = sigm(acc[1]);
                float g_ = tanhf_(acc[2]);
                float o_ = sigm(acc[3]);
                creg0[m] = f_ * creg0[m] + i_ * g_;
                int us = (int)(u32)(unsigned short)f2bs(o_ * tanhf_(creg0[m]));
                int other = __shfl_xor(us, 16);          // q <-> q^1 partner
                if ((q & 1) == 0)
                    hs0[par ^ 1][ln * 132 + mt * 2 + (q >> 1)] =
                        (u32)us | ((u32)other << 16);
            }
        }
        __syncthreads();                  // B1: h0(t) visible

        // h1(t-1) frags (also the out-proj B operand)
        bf16x8 hb1[8];
        {
            const unsigned short* p1 = (const unsigned short*)hs1[par];
            #pragma unroll
            for (int kk = 0; kk < 8; kk++)
                hb1[kk] = *(const bf16x8*)(p1 + ln * 264 + kk * 32 + q * 8);
        }

        // ---- layer 1: h1(t) = lstm(h0(t), h1(t-1)) ----
        if (t < SEQ) {
            bf16x8 hb0n[8];
            const unsigned short* p0n = (const unsigned short*)hs0[par ^ 1];
            #pragma unroll
            for (int kk = 0; kk < 8; kk++)
                hb0n[kk] = *(const bf16x8*)(p0n + ln * 264 + kk * 32 + q * 8);
            #pragma unroll
            for (int m = 0; m < 8; m++) {
                const int mt = w8 + m;
                const short* ap1 = W1p + mt * 4096 + lane8;
                const short* ap2 = W2p + mt * 4096 + lane8;
                f32x4 accA, accB = {0.f, 0.f, 0.f, 0.f};
                accA[0] = bs2f((unsigned short)(gx1p[m][0] & 0xFFFFu));
                accA[1] = bs2f((unsigned short)(gx1p[m][0] >> 16));
                accA[2] = bs2f((unsigned short)(gx1p[m][1] & 0xFFFFu));
                accA[3] = bs2f((unsigned short)(gx1p[m][1] >> 16));
                #pragma unroll
                for (int kk = 0; kk < 8; kk++) {
                    accA = __builtin_amdgcn_mfma_f32_16x16x32_bf16(
                        *(const bf16x8*)(ap1 + kk * 512), hb0n[kk], accA, 0, 0, 0);
                    accB = __builtin_amdgcn_mfma_f32_16x16x32_bf16(
                        *(const bf16x8*)(ap2 + kk * 512), hb1[kk], accB, 0, 0, 0);
                }
                float i_ = sigm(accA[0] + accB[0]);
                float f_ = sigm(accA[1] + accB[1]);
                float g_ = tanhf_(accA[2] + accB[2]);
                float o_ = sigm(accA[3] + accB[3]);
                creg1[m] = f_ * creg1[m] + i_ * g_;
                int us = (int)(u32)(unsigned short)f2bs(o_ * tanhf_(creg1[m]));
                int other = __shfl_xor(us, 16);
                if ((q & 1) == 0)
                    hs1[par ^ 1][ln * 132 + mt * 2 + (q >> 1)] =
                        (u32)us | ((u32)other << 16);
            }
        }

        // ---- out-proj for step t-1 (reuses hb1 = h1(t-1)); waves 0..3 ----
        if (w < 4 && t >= 1) {
            const short* apo = Wop + w * 4096 + lane8;
            f32x4 acc;
            acc[0] = bor[0]; acc[1] = bor[1]; acc[2] = bor[2]; acc[3] = bor[3];
            #pragma unroll
            for (int kk = 0; kk < 8; kk++)
                acc = __builtin_amdgcn_mfma_f32_16x16x32_bf16(
                    *(const bf16x8*)(apo + kk * 512), hb1[kk], acc, 0, 0, 0);
            *(f32x4*)&out[(long)myb * (SEQ * OUTD) + (t - 1) * OUTD + w * 16 + q * 4] = acc;
        }
        __syncthreads();                  // B2: plane par free for t+1 writes
    }
}

extern "C" void kernel_launch(void* const* d_in, const int* in_sizes, int n_in,
                              void* d_out, int out_size, void* d_ws, size_t ws_size,
                              hipStream_t stream) {
    const float* z     = (const float*)d_in[0];
    const float* Whid  = (const float*)d_in[1];
    const float* bhid  = (const float*)d_in[2];
    const float* Wcell = (const float*)d_in[3];
    const float* bcell = (const float*)d_in[4];
    const float* Win   = (const float*)d_in[5];
    const float* bin   = (const float*)d_in[6];
    const float* Wih0  = (const float*)d_in[7];
    const float* Whh0  = (const float*)d_in[8];
    const float* bih0  = (const float*)d_in[9];
    const float* bhh0  = (const float*)d_in[10];
    const float* Wih1  = (const float*)d_in[11];
    const float* Whh1  = (const float*)d_in[12];
    const float* bih1  = (const float*)d_in[13];
    const float* bhh1  = (const float*)d_in[14];
    const float* Wout  = (const float*)d_in[15];
    const float* bout  = (const float*)d_in[16];
    float* out = (float*)d_out;

    // workspace: packed weight frags only — 1,605,632 B (< 2,101,248 proven)
    short* Wp = (short*)d_ws;

    lstm_pack_w<<<392, 256, 0, stream>>>(Whh0, Wih1, Whh1, Wout, Wp);
    lstm_fused<<<16, 512, 0, stream>>>(z, Whid, bhid, Wcell, bcell, Win, bin,
                                       Wih0, bih0, bhh0, bih1, bhh1, bout,
                                       Wp, out);
}

// Round 10
// 1499.459 us; speedup vs baseline: 12.4028x; 12.4028x over previous
//
#include <hip/hip_runtime.h>
#include <hip/hip_bf16.h>

#define LAT 128
#define H 256
#define OUTD 64
#define SEQ 512

typedef short bf16x8 __attribute__((ext_vector_type(8)));
typedef float f32x4  __attribute__((ext_vector_type(4)));
typedef unsigned long long u64;
typedef unsigned u32;

__device__ __forceinline__ float sigm(float x)  { return 1.f / (1.f + __expf(-x)); }
__device__ __forceinline__ float tanhf_(float x){ return 1.f - 2.f / (__expf(2.f * x) + 1.f); }

__device__ __forceinline__ short f2bs(float x) {
    __hip_bfloat16 b = __float2bfloat16(x);
    return *reinterpret_cast<short*>(&b);
}
__device__ __forceinline__ float bs2f(unsigned short h) {
    u32 b = ((u32)h) << 16;
    float f; __builtin_memcpy(&f, &b, 4); return f;
}
__device__ __forceinline__ u32 f2pair(float a, float b) {
    return ((u32)(unsigned short)f2bs(b) << 16) | (u32)(unsigned short)f2bs(a);
}
__device__ __forceinline__ bf16x8 pack8(const float* s) {
    bf16x8 v;
    v[0]=f2bs(s[0]); v[1]=f2bs(s[1]); v[2]=f2bs(s[2]); v[3]=f2bs(s[3]);
    v[4]=f2bs(s[4]); v[5]=f2bs(s[5]); v[6]=f2bs(s[6]); v[7]=f2bs(s[7]);
    return v;
}

// ---- Transport: AGENT scope. SESSION-BEST configuration (R5: 1497us bench,
// 1353-1366us steady dispatches). Ledger of probed-and-rejected alternatives:
//  R1 RMW publish (0) | R2 per-line accept (--) | R3 merged polls (-)
//  R4 load-before-store vmcnt decoupling (-4.5%, KEPT) | R6 8-wg clusters (--)
//  R7 consecutive-slot staging (--, destroys coalescing) | R8 early h0
//  prefetch (-) | R9 fused single-wg recurrence (---, serial L2 latency).
// The ~6330cy/step period is the floor of the 2-handoff/16-producer global
// transport; register-pinned weights are the load-bearing feature.
__device__ __forceinline__ u64 sys_load_u64(const u64* p) {
    return __hip_atomic_load((u64*)p, __ATOMIC_RELAXED, __HIP_MEMORY_SCOPE_AGENT);
}
__device__ __forceinline__ void sys_store_u64(u64* p, u64 v) {
    __hip_atomic_store(p, v, __ATOMIC_RELAXED, __HIP_MEMORY_SCOPE_AGENT);
}

// ---------------- Prologue 1: tagged h-init, c-init, L1 bias ----
__global__ void lstm_prologue_init(const float* __restrict__ z,
                                   const float* __restrict__ Whid,
                                   const float* __restrict__ bhid,
                                   const float* __restrict__ Wcell,
                                   const float* __restrict__ bcell,
                                   const float* __restrict__ bih1,
                                   const float* __restrict__ bhh1,
                                   u64* __restrict__ h0B1,
                                   u64* __restrict__ h1B1,
                                   float* __restrict__ c0,
                                   float* __restrict__ c1,
                                   float* __restrict__ gxb1)
{
    int t = blockIdx.x * 256 + threadIdx.x;
    if (t < 65536) {                     // tagged hidden-init: 2 layers x 256 b x 128 pairs
        int layer = t >> 15;
        int tt = t & 32767;
        int b = tt >> 7, cp = tt & 127;
        int colA = layer * H + 2 * cp;
        const float* zr = z + b * LAT;
        const float* wA = Whid + colA * LAT;
        const float* wB = wA + LAT;
        float a0 = bhid[colA], a1 = bhid[colA + 1];
        for (int k = 0; k < LAT; k++) { float zv = zr[k]; a0 += zv * wA[k]; a1 += zv * wB[k]; }
        u64 v = ((u64)(u32)layer << 32) | (u64)f2pair(a0, a1);
        (layer ? h1B1 : h0B1)[b * 128 + cp] = v;
    } else if (t < 196608) {             // cell init: [256 x 512]
        int tt = t - 65536;
        int b = tt >> 9, col = tt & 511;
        const float* w  = Wcell + col * LAT;
        const float* zr = z + b * LAT;
        float acc = bcell[col];
        for (int k = 0; k < LAT; k++) acc += zr[k] * w[k];
        if (col < H) c0[b * H + col] = acc;
        else         c1[b * H + (col - H)] = acc;
    } else if (t < 197632) {             // layer-1 gate bias vector [1024]
        int g = t - 196608;
        gxb1[g] = bih1[g] + bhh1[g];
    }
}

// ---------------- Prologue 2: gx0 packed bf16 pairs ----
__global__ void lstm_prologue_gx0(const float* __restrict__ z,
                                  const float* __restrict__ Win,
                                  const float* __restrict__ bin,
                                  const float* __restrict__ Wih0,
                                  const float* __restrict__ bih0,
                                  const float* __restrict__ bhh0,
                                  u32* __restrict__ gxb0u)
{
    __shared__ float xs[H];
    const int b = blockIdx.y;
    const int tid = threadIdx.x;
    {
        const float* w  = Win + tid * LAT;
        const float* zr = z + b * LAT;
        float acc = bin[tid];
        for (int k = 0; k < LAT; k++) acc += zr[k] * w[k];
        xs[tid] = acc;
    }
    __syncthreads();
    const int cA = blockIdx.x * 512 + 2 * tid;
    const float* wA = Wih0 + cA * H;
    const float* wB = wA + H;
    float a0 = bih0[cA]     + bhh0[cA];
    float a1 = bih0[cA + 1] + bhh0[cA + 1];
    for (int k = 0; k < H; k++) { float xv = xs[k]; a0 += xv * wA[k]; a1 += xv * wB[k]; }
    gxb0u[b * 512 + blockIdx.x * 256 + tid] = f2pair(a0, a1);
}

// ---------------- Persistent kernel ----------------
// 256 wgs x 256 thr. Cluster bg = wg>>4, wg j = wg&15 owns 16 hidden cols.
// Two barriers, R0 poll positions, snapshot reload-all spins, agent scope,
// load-before-store vmcnt decoupling (R4), L1 dual accumulators (R5).
__global__ __launch_bounds__(256, 1)
void lstm_persistent(const u32* __restrict__ gxb0u, const float* __restrict__ gxb1,
                     const float* __restrict__ c0g, const float* __restrict__ c1g,
                     u64* __restrict__ h0B0, u64* __restrict__ h0B1,
                     u64* __restrict__ h1B0, u64* __restrict__ h1B1,
                     const float* __restrict__ Whh0, const float* __restrict__ Wih1,
                     const float* __restrict__ Whh1, const float* __restrict__ Wout,
                     const float* __restrict__ bout, float* __restrict__ out)
{
    const int wg = blockIdx.x;
    const int bg = wg >> 4;
    const int j  = wg & 15;
    const int tid  = threadIdx.x;
    const int wave = tid >> 6;
    const int q  = (tid >> 4) & 3;
    const int ln = tid & 15;
    const int mycol = j * 16 + wave * 4 + q;
    const int myb   = bg * 16 + ln;

    __shared__ u32 hs0[2][16 * 132];           // parity planes, row-major packed pairs
    __shared__ u32 hs1[2][16 * 132];

    // ---- A-frags: packed-gate weight rows (m = c*4 + g) ----
    bf16x8 wf[3][8];
    {
        const float* mats[3] = { Whh0, Wih1, Whh1 };
        const int arow = (ln & 3) * H + j * 16 + wave * 4 + (ln >> 2);
        #pragma unroll
        for (int mm = 0; mm < 3; mm++) {
            const float* s = mats[mm] + arow * H;
            #pragma unroll
            for (int kk = 0; kk < 8; kk++) wf[mm][kk] = pack8(s + kk * 32 + q * 8);
        }
    }
    const bool doOut = (j < 4) && (wave == 0);
    bf16x8 wo[8];
    float bor[4] = {0.f, 0.f, 0.f, 0.f};
    if (doOut) {
        const int orow = j * 16 + ln;          // natural rows: C m = out-col
        const float* s = Wout + orow * H;
        #pragma unroll
        for (int kk = 0; kk < 8; kk++) wo[kk] = pack8(s + kk * 32 + q * 8);
        #pragma unroll
        for (int r = 0; r < 4; r++) bor[r] = bout[j * 16 + q * 4 + r];
    }

    // ---- per-lane gate biases + cell state ----
    float gxr0[4], gxr1[4];
    #pragma unroll
    for (int r = 0; r < 4; r++) {
        u32 v = gxb0u[myb * 512 + ((r * 256 + mycol) >> 1)];
        gxr0[r] = bs2f((unsigned short)((mycol & 1) ? (v >> 16) : (v & 0xFFFFu)));
        gxr1[r] = gxb1[r * 256 + mycol];
    }
    float creg0 = c0g[myb * H + mycol];
    float creg1 = c1g[myb * H + mycol];

    u64* A0 = h0B0 + bg * 2048;   // cluster slices: 16 rows x 128 pair-slots
    u64* A1 = h0B1 + bg * 2048;
    u64* B0 = h1B0 + bg * 2048;
    u64* B1 = h1B1 + bg * 2048;

    const int pubslot = ln * 128 + j * 8 + wave * 2 + (q >> 1);   // even-q lanes
    const bool pubLane = ((q & 1) == 0);

    // ---- carried h0 poll regs; preloop: k=0 snapshot from A1 (prologue tag 0) ----
    u64 v0[8];
    #pragma unroll
    for (int i = 0; i < 8; i++) v0[i] = sys_load_u64(A1 + i * 256 + tid);

    for (int k = 0; k <= SEQ + 1; k++) {
        const u64* P1 = (k & 1) ? B1 : B0;  u64* C1 = (k & 1) ? B0 : B1;
        u64* C0 = (k & 1) ? A1 : A0;
        const int par = k & 1;

        // ---- TOP staging: h0 (carried snapshot check; reload-all fallback) ----
        if (k <= SEQ) {
            const u64* P0 = (k & 1) ? A0 : A1;
            bool ok = true;
            #pragma unroll
            for (int i = 0; i < 8; i++) ok = ok && ((u32)(v0[i] >> 32) == (u32)k);
            int guard = 0;
            while (!ok && guard < 16384) {
                ok = true;
                #pragma unroll
                for (int i = 0; i < 8; i++) v0[i] = sys_load_u64(P0 + i * 256 + tid);
                #pragma unroll
                for (int i = 0; i < 8; i++) ok = ok && ((u32)(v0[i] >> 32) == (u32)k);
                guard++;
            }
            u32* dst = hs0[par];
            #pragma unroll
            for (int i = 0; i < 8; i++) { int s = i * 256 + tid; dst[(s >> 7) * 132 + (s & 127)] = (u32)v0[i]; }
        }
        __syncthreads();                       // B1

        // ---- h0 B-frags (batch row ln) ----
        bf16x8 hb0[8];
        {
            const unsigned short* b0p = (const unsigned short*)hs0[par];
            #pragma unroll
            for (int kk = 0; kk < 8; kk++)
                hb0[kk] = *(const bf16x8*)(b0p + ln * 264 + kk * 32 + q * 8);
        }

        // ---- issue h1 tag-k poll loads NOW (~0.35T cover to the MID check;
        //      older than the L0 publish store -> check excludes store ack) ----
        u64 v1[8];
        if (k >= 1) {
            #pragma unroll
            for (int i = 0; i < 8; i++) v1[i] = sys_load_u64(P1 + i * 256 + tid);
        }
        __builtin_amdgcn_sched_barrier(0);     // pin: loads issued before L0 block

        // ---- layer 0, step k: gates in acc, publish from regs ----
        if (k < SEQ) {
            f32x4 acc = {0.f, 0.f, 0.f, 0.f};
            #pragma unroll
            for (int kk = 0; kk < 8; kk++)
                acc = __builtin_amdgcn_mfma_f32_16x16x32_bf16(wf[0][kk], hb0[kk], acc, 0, 0, 0);
            float i_ = sigm(acc[0] + gxr0[0]);
            float f_ = sigm(acc[1] + gxr0[1]);
            float g_ = tanhf_(acc[2] + gxr0[2]);
            float o_ = sigm(acc[3] + gxr0[3]);
            creg0 = f_ * creg0 + i_ * g_;
            int us = (int)(u32)(unsigned short)f2bs(o_ * tanhf_(creg0));
            int other = __shfl_xor(us, 16);    // q <-> q^1 (col pair partner)
            if (pubLane) {
                u32 pa = (u32)us | ((u32)other << 16);
                sys_store_u64(C0 + pubslot, ((u64)(u32)(k + 1) << 32) | (u64)pa);
            }
        }

        // ---- MID staging: h1 (check prefetched snapshot; reload-all fallback) ----
        if (k >= 1) {
            bool ok = true;
            #pragma unroll
            for (int i = 0; i < 8; i++) ok = ok && ((u32)(v1[i] >> 32) == (u32)k);
            int guard = 0;
            while (!ok && guard < 16384) {
                ok = true;
                #pragma unroll
                for (int i = 0; i < 8; i++) v1[i] = sys_load_u64(P1 + i * 256 + tid);
                #pragma unroll
                for (int i = 0; i < 8; i++) ok = ok && ((u32)(v1[i] >> 32) == (u32)k);
                guard++;
            }
            u32* dst = hs1[par];
            #pragma unroll
            for (int i = 0; i < 8; i++) { int s = i * 256 + tid; dst[(s >> 7) * 132 + (s & 127)] = (u32)v1[i]; }
        }
        __syncthreads();                       // B2

        // ---- h1 B-frags ----
        bf16x8 hb1[8];
        {
            const unsigned short* b1p = (const unsigned short*)hs1[par];
            #pragma unroll
            for (int kk = 0; kk < 8; kk++)
                hb1[kk] = *(const bf16x8*)(b1p + ln * 264 + kk * 32 + q * 8);
        }

        // ---- layer 1, step k-1: two independent acc chains (8+8 pipelined) ----
        u32 pa1 = 0; bool pub1 = false;
        if (k >= 1 && k <= SEQ) {
            f32x4 accA = {0.f, 0.f, 0.f, 0.f};
            f32x4 accB = {0.f, 0.f, 0.f, 0.f};
            #pragma unroll
            for (int kk = 0; kk < 8; kk++) {
                accA = __builtin_amdgcn_mfma_f32_16x16x32_bf16(wf[1][kk], hb0[kk], accA, 0, 0, 0);
                accB = __builtin_amdgcn_mfma_f32_16x16x32_bf16(wf[2][kk], hb1[kk], accB, 0, 0, 0);
            }
            float i_ = sigm(accA[0] + accB[0] + gxr1[0]);
            float f_ = sigm(accA[1] + accB[1] + gxr1[1]);
            float g_ = tanhf_(accA[2] + accB[2] + gxr1[2]);
            float o_ = sigm(accA[3] + accB[3] + gxr1[3]);
            creg1 = f_ * creg1 + i_ * g_;
            int us = (int)(u32)(unsigned short)f2bs(o_ * tanhf_(creg1));
            int other = __shfl_xor(us, 16);
            pa1 = (u32)us | ((u32)other << 16);
            pub1 = pubLane;
        }

        // ---- LATE h0 prefetch for k+1 (published at ~0.4T this iter by all
        //      wgs). Issued BEFORE the L1 publish store so the top-of-(k+1)
        //      check's counted vmcnt excludes the store ack. ----
        if (k < SEQ) {
            #pragma unroll
            for (int i = 0; i < 8; i++) v0[i] = sys_load_u64(C0 + i * 256 + tid);
        }
        __builtin_amdgcn_sched_barrier(0);     // pin: prefetch before publish store

        // ---- layer-1 publish (store younger than all poll loads) ----
        if (pub1) {
            sys_store_u64(C1 + pubslot, ((u64)(u32)(k + 1) << 32) | (u64)pa1);
        }

        // ---- output projection, step k-2 (reuses hb1 = h1_{k-2}); f32x4 store ----
        if (k >= 2 && doOut) {
            f32x4 acc = {0.f, 0.f, 0.f, 0.f};
            #pragma unroll
            for (int kk = 0; kk < 8; kk++)
                acc = __builtin_amdgcn_mfma_f32_16x16x32_bf16(wo[kk], hb1[kk], acc, 0, 0, 0);
            f32x4 res;
            #pragma unroll
            for (int r = 0; r < 4; r++) res[r] = acc[r] + bor[r];
            *(f32x4*)&out[(bg * 16 + ln) * (SEQ * OUTD) + (k - 2) * OUTD + j * 16 + q * 4] = res;
        }
    }
}

extern "C" void kernel_launch(void* const* d_in, const int* in_sizes, int n_in,
                              void* d_out, int out_size, void* d_ws, size_t ws_size,
                              hipStream_t stream) {
    const float* z     = (const float*)d_in[0];
    const float* Whid  = (const float*)d_in[1];
    const float* bhid  = (const float*)d_in[2];
    const float* Wcell = (const float*)d_in[3];
    const float* bcell = (const float*)d_in[4];
    const float* Win   = (const float*)d_in[5];
    const float* bin   = (const float*)d_in[6];
    const float* Wih0  = (const float*)d_in[7];
    const float* Whh0  = (const float*)d_in[8];
    const float* bih0  = (const float*)d_in[9];
    const float* bhh0  = (const float*)d_in[10];
    const float* Wih1  = (const float*)d_in[11];
    const float* Whh1  = (const float*)d_in[12];
    const float* bih1  = (const float*)d_in[13];
    const float* bhh1  = (const float*)d_in[14];
    const float* Wout  = (const float*)d_in[15];
    const float* bout  = (const float*)d_in[16];
    float* out = (float*)d_out;

    // workspace: 2,101,248 B total (proven size)
    u32*   gxb0u = (u32*)d_ws;                   // [131072] bf16-pair gate biases
    float* gxb1  = (float*)(gxb0u + 131072);     // [1024]
    float* c0    = gxb1 + 1024;                  // [65536]
    float* c1    = c0 + 65536;                   // [65536]
    u64*   h0B0  = (u64*)(c1 + 65536);           // [32768] tagged pair-slots x4
    u64*   h0B1  = h0B0 + 32768;
    u64*   h1B0  = h0B1 + 32768;
    u64*   h1B1  = h1B0 + 32768;

    lstm_prologue_init<<<772, 256, 0, stream>>>(z, Whid, bhid, Wcell, bcell,
                                                bih1, bhh1, h0B1, h1B1, c0, c1, gxb1);
    lstm_prologue_gx0<<<dim3(2, 256), 256, 0, stream>>>(z, Win, bin, Wih0, bih0, bhh0, gxb0u);

    void* kargs[] = { (void*)&gxb0u, (void*)&gxb1, (void*)&c0, (void*)&c1,
                      (void*)&h0B0, (void*)&h0B1, (void*)&h1B0, (void*)&h1B1,
                      (void*)&Whh0, (void*)&Wih1, (void*)&Whh1, (void*)&Wout,
                      (void*)&bout, (void*)&out };
    hipError_t ce = hipLaunchCooperativeKernel((const void*)lstm_persistent,
                                               dim3(256), dim3(256), kargs, 0, stream);
    if (ce != hipSuccess) {
        lstm_persistent<<<256, 256, 0, stream>>>(gxb0u, gxb1, c0, c1,
                                                 h0B0, h0B1, h1B0, h1B1,
                                                 Whh0, Wih1, Whh1, Wout, bout, out);
    }
}